// Round 2
// 1024.682 us; speedup vs baseline: 1.0859x; 1.0859x over previous
//
#include <hip/hip_runtime.h>
#include <math.h>

#define B 32
#define C 256
#define H 128
#define W 128
#define HW (H * W)

#define CSLICES 16
#define CPS (C / CSLICES)   // 16 channels per slice

typedef float f32x4 __attribute__((ext_vector_type(4)));

// ws layout (floats) -- every region fully written before read each launch
//   [0,      8192)    pooled sums  (B*C)
//   [8192,   8480)    per-sample 3x3 kernels (B*9)
//   [16384,  540672)  att map (B*HW)
//   [540672, 8929280) x_mean partials (CSLICES * B * HW)
#define WS_POOLED 0
#define WS_KER    8192
#define WS_ATT    16384
#define WS_PART   540672

// ---------------------------------------------------------------------------
// k1: block = (b, 16-channel slice), reads a contiguous 1 MiB of x.
//   x_mean partial: per-thread register accumulation over the slice's
//   channels -> float4 stores to the per-slice partial buffer.
//   pooled: per (b,c) lives entirely in this block -> LDS transpose +
//   4 shuffles per thread, direct store. No atomics, no memset.
// ---------------------------------------------------------------------------
__global__ __launch_bounds__(256) void k1_reduce(const float* __restrict__ x,
                                                 float* __restrict__ pooled_sum,
                                                 float* __restrict__ part) {
    const int blk = blockIdx.x;
    const int b   = blk >> 4;
    const int cs  = blk & 15;
    const int t   = threadIdx.x;

    __shared__ float plds[CPS][257];   // +1 pad: conflict-free column reduce

    const float* xb = x + (size_t)b * C * HW + (size_t)cs * CPS * HW + 4 * t;

    f32x4 xm[16];
    #pragma unroll
    for (int i = 0; i < 16; ++i) xm[i] = (f32x4)(0.f);

    #pragma unroll 2
    for (int ch = 0; ch < CPS; ++ch) {
        const float* xc = xb + (size_t)ch * HW;
        float p = 0.f;
        #pragma unroll
        for (int i = 0; i < 16; ++i) {
            const f32x4 v =
                __builtin_nontemporal_load((const f32x4*)(xc + i * 1024));
            xm[i] += v;
            p += (v.x + v.y) + (v.z + v.w);
        }
        plds[ch][t] = p;
    }

    // x_mean partial slice (raw sums over this slice's 16 channels)
    float* pp = part + ((size_t)cs * B + b) * HW + 4 * t;
    #pragma unroll
    for (int i = 0; i < 16; ++i)
        *(f32x4*)(pp + i * 1024) = xm[i];

    __syncthreads();
    // pooled[b, cs*16 + ch] = sum over 256 thread-partials
    const int ch = t >> 4;
    const int g  = t & 15;
    float s = 0.f;
    #pragma unroll
    for (int j = 0; j < 16; ++j) s += plds[ch][g + 16 * j];
    #pragma unroll
    for (int m = 8; m >= 1; m >>= 1) s += __shfl_xor(s, m, 64);
    if (g == 0) pooled_sum[b * C + cs * CPS + ch] = s;
}

// ---------------------------------------------------------------------------
// k2: per-sample MLP.  z = relu(pooled @ w1 + b1); ker = z @ w2 + b2.
// ---------------------------------------------------------------------------
__global__ __launch_bounds__(256) void k2_mlp(const float* __restrict__ pooled_sum,
                                              const float* __restrict__ w1,
                                              const float* __restrict__ b1,
                                              const float* __restrict__ w2,
                                              const float* __restrict__ b2,
                                              float* __restrict__ kernels) {
    const int b = blockIdx.x;
    const int t = threadIdx.x;
    __shared__ float p[C];
    __shared__ float z[C];

    p[t] = pooled_sum[b * C + t] * (1.0f / (float)HW);
    __syncthreads();

    float acc = b1[t];
    #pragma unroll 8
    for (int c = 0; c < C; ++c)
        acc = fmaf(p[c], w1[c * C + t], acc);
    z[t] = fmaxf(acc, 0.f);
    __syncthreads();

    if (t < 9) {
        float k = b2[t];
        for (int j = 0; j < C; ++j)
            k = fmaf(z[j], w2[j * 9 + t], k);
        kernels[b * 9 + t] = k;
    }
}

// ---------------------------------------------------------------------------
// k2b: reduce the 16 x_mean partials into a zero-padded 10x132 LDS tile,
//      3x3 conv + sigmoid once per tile, write att (2 MiB).
//   grid = B * 16, block (b, rowblock) owns output rows [rb*8, rb*8+8).
// ---------------------------------------------------------------------------
__global__ __launch_bounds__(256) void k2b_att(const float* __restrict__ part,
                                               const float* __restrict__ kernels,
                                               float* __restrict__ att) {
    const int blk  = blockIdx.x;
    const int rb   = blk & 15;
    const int b    = blk >> 4;
    const int row0 = rb * 8;
    const int t    = threadIdx.x;

    __shared__ float xm_t[10][132];   // rows row0-1..row0+8, col offset +1, zero-padded
    __shared__ float ker[9];
    if (t < 9) ker[t] = kernels[b * 9 + t];

    for (int idx = t; idx < 10 * 132; idx += 256) ((float*)xm_t)[idx] = 0.f;
    __syncthreads();

    const float invC = 1.0f / (float)C;
    for (int idx = t; idx < 1280; idx += 256) {
        const int r  = idx >> 7;
        const int wl = idx & 127;
        const int hh = row0 - 1 + r;
        if (hh >= 0 && hh < H) {
            float s = 0.f;
            #pragma unroll
            for (int sl = 0; sl < CSLICES; ++sl)
                s += part[((size_t)sl * B + b) * HW + hh * W + wl];
            xm_t[r][1 + wl] = s * invC;
        }
    }
    __syncthreads();

    #pragma unroll
    for (int i = 0; i < 4; ++i) {
        const int pos = t + i * 256;
        const int h   = pos >> 7;
        const int w   = pos & 127;
        float a = 0.f;
        #pragma unroll
        for (int dy = 0; dy < 3; ++dy)
            #pragma unroll
            for (int dx = 0; dx < 3; ++dx)
                a = fmaf(xm_t[h + dy][w + dx], ker[dy * 3 + dx], a);
        att[(size_t)b * HW + (size_t)(row0 + h) * W + w] =
            1.0f / (1.0f + __expf(-a));
    }
}

// ---------------------------------------------------------------------------
// k3: pure streaming out = x * att. No LDS, no barriers.
//   grid = B * 16 * 4; blk -> (b, rowblock, cslice).
// ---------------------------------------------------------------------------
#define ROWS 8
#define CSPLIT 4
#define CPB (C / CSPLIT)

__global__ __launch_bounds__(256) void k3_apply(const float* __restrict__ x,
                                                const float* __restrict__ att,
                                                float* __restrict__ out) {
    const int blk  = blockIdx.x;
    const int cs   = blk & (CSPLIT - 1);
    const int rb   = (blk >> 2) & 15;
    const int b    = blk >> 6;
    const int row0 = rb * ROWS;
    const int t    = threadIdx.x;

    const f32x4 av =
        *(const f32x4*)(att + (size_t)b * HW + (size_t)row0 * W + 4 * t);
    const size_t base = (size_t)b * C * HW + (size_t)row0 * W + 4 * t;
    const int c0 = cs * CPB;
    #pragma unroll 4
    for (int c = c0; c < c0 + CPB; ++c) {
        const f32x4 v = __builtin_nontemporal_load(
            (const f32x4*)(x + base + (size_t)c * HW));
        const f32x4 o = v * av;
        __builtin_nontemporal_store(o, (f32x4*)(out + base + (size_t)c * HW));
    }
}

extern "C" void kernel_launch(void* const* d_in, const int* in_sizes, int n_in,
                              void* d_out, int out_size, void* d_ws, size_t ws_size,
                              hipStream_t stream) {
    (void)in_sizes; (void)n_in; (void)out_size; (void)ws_size;
    const float* x  = (const float*)d_in[0];
    const float* w1 = (const float*)d_in[1];
    const float* b1 = (const float*)d_in[2];
    const float* w2 = (const float*)d_in[3];
    const float* b2 = (const float*)d_in[4];
    float* out = (float*)d_out;
    float* ws  = (float*)d_ws;

    float* pooled = ws + WS_POOLED;
    float* kers   = ws + WS_KER;
    float* att    = ws + WS_ATT;
    float* part   = ws + WS_PART;

    k1_reduce<<<B * CSLICES, 256, 0, stream>>>(x, pooled, part);
    k2_mlp<<<B, 256, 0, stream>>>(pooled, w1, b1, w2, b2, kers);
    k2b_att<<<B * 16, 256, 0, stream>>>(part, kers, att);
    k3_apply<<<B * 16 * CSPLIT, 256, 0, stream>>>(x, att, out);
}